// Round 2
// baseline (16649.200 us; speedup 1.0000x reference)
//
#include <hip/hip_runtime.h>
#include <math.h>

#define B_   64
#define S_   512
#define E_   256
#define H_   256
#define G4H_ 1024
#define NT_  24

// ---- workspace layout (float-element offsets, all small state at offset 0) ----
// hbuf  : [2 slot][2 dir][H][B] = 65,536 f   (zeroed each launch)
// flags : 1024 ints                          (zeroed each launch)
// cstate: [2][B][H] = 32,768 f               (written by chunk 0 before read)
// emisF : [B][S][NT] = 786,432 f
// emisB : [B][S][NT] = 786,432 f
// hout_c: [2][tc][B][H]   = tc*32,768 f
// xpre_c: [2][tc][B][4H]  = tc*131,072 f
static const size_t HBUF_OFF  = 0;
static const size_t FLAG_OFF  = 65536;
static const size_t CST_OFF   = 66560;
static const size_t EMF_OFF   = 99328;
static const size_t EMB_OFF   = 885760;
static const size_t HOUT_OFF  = 1672192;

__device__ __forceinline__ float sigmoidf_(float x) {
  return 1.0f / (1.0f + expf(-x));
}

// ============================================================================
// K1: xpre_c[d][lt][b][:] = emb[x[b][tok]] @ Wih_d^T + (bih_d + bhh_d)
// tok = d ? S-1-(c*tc+lt) : c*tc+lt.  GEMM rows m=lt*64+b (tc*64 per dir),
// N=1024, K=256; 128x128 tiles, k-chunks of 32. grid = 8*tc, block = 256.
// ============================================================================
__global__ __launch_bounds__(256) void k1_xpre(
    const int* __restrict__ x, const float* __restrict__ emb,
    const float* __restrict__ Wih_f, const float* __restrict__ bih_f,
    const float* __restrict__ bhh_f, const float* __restrict__ Wih_b,
    const float* __restrict__ bih_b, const float* __restrict__ bhh_b,
    float* __restrict__ xpre_c, int chunk, int tc)
{
  __shared__ float As[32][132];   // [k][m]
  __shared__ float Bs[32][132];   // [k][n]
  __shared__ int   xt[128];

  const int tid = threadIdx.x;
  const int wg  = blockIdx.x;
  const int per_dir = 4 * tc;
  const int d   = wg / per_dir;
  const int rem = wg % per_dir;
  const int m0  = (rem >> 3) * 128;
  const int n0  = (rem & 7) * 128;
  const int t0  = chunk * tc;

  const float* Wih = d ? Wih_b : Wih_f;
  const float* bih = d ? bih_b : bih_f;
  const float* bhh = d ? bhh_b : bhh_f;

  if (tid < 128) {
    int m = m0 + tid;
    int lt = m >> 6, b = m & 63;
    int tok = d ? (S_ - 1 - (t0 + lt)) : (t0 + lt);
    xt[tid] = x[b * S_ + tok];
  }
  __syncthreads();

  float acc[8][8];
#pragma unroll
  for (int i = 0; i < 8; ++i)
#pragma unroll
    for (int j = 0; j < 8; ++j) acc[i][j] = 0.0f;

  const int mt8 = tid & 15;    // 16 m-groups of 8 rows
  const int nt8 = tid >> 4;    // 16 n-groups of 8 cols
  const int q = tid & 7, rbase = tid >> 3;

  for (int kc = 0; kc < 8; ++kc) {
    const int k0 = kc * 32;
#pragma unroll
    for (int i = 0; i < 4; ++i) {
      int row = rbase + i * 32;
      float4 a = *(const float4*)(emb + (long)xt[row] * E_ + k0 + q * 4);
      As[q * 4 + 0][row] = a.x; As[q * 4 + 1][row] = a.y;
      As[q * 4 + 2][row] = a.z; As[q * 4 + 3][row] = a.w;
      float4 w = *(const float4*)(Wih + (long)(n0 + row) * E_ + k0 + q * 4);
      Bs[q * 4 + 0][row] = w.x; Bs[q * 4 + 1][row] = w.y;
      Bs[q * 4 + 2][row] = w.z; Bs[q * 4 + 3][row] = w.w;
    }
    __syncthreads();
#pragma unroll
    for (int k = 0; k < 32; ++k) {
      float4 a0 = *(float4*)&As[k][mt8 * 8];
      float4 a1 = *(float4*)&As[k][mt8 * 8 + 4];
      float4 b0 = *(float4*)&Bs[k][nt8 * 8];
      float4 b1 = *(float4*)&Bs[k][nt8 * 8 + 4];
      float am[8] = {a0.x, a0.y, a0.z, a0.w, a1.x, a1.y, a1.z, a1.w};
      float bn[8] = {b0.x, b0.y, b0.z, b0.w, b1.x, b1.y, b1.z, b1.w};
#pragma unroll
      for (int i = 0; i < 8; ++i)
#pragma unroll
        for (int j = 0; j < 8; ++j) acc[i][j] = fmaf(am[i], bn[j], acc[i][j]);
    }
    __syncthreads();
  }

  float bias[8];
  {
    float4 u0 = *(const float4*)(bih + n0 + nt8 * 8);
    float4 u1 = *(const float4*)(bih + n0 + nt8 * 8 + 4);
    float4 v0 = *(const float4*)(bhh + n0 + nt8 * 8);
    float4 v1 = *(const float4*)(bhh + n0 + nt8 * 8 + 4);
    bias[0] = u0.x + v0.x; bias[1] = u0.y + v0.y; bias[2] = u0.z + v0.z;
    bias[3] = u0.w + v0.w; bias[4] = u1.x + v1.x; bias[5] = u1.y + v1.y;
    bias[6] = u1.z + v1.z; bias[7] = u1.w + v1.w;
  }
#pragma unroll
  for (int i = 0; i < 8; ++i) {
    int m = m0 + mt8 * 8 + i;
    int lt = m >> 6, b = m & 63;
    float* o = xpre_c + ((size_t)(d * tc + lt) * B_ + b) * G4H_ + n0 + nt8 * 8;
    float4 r0, r1;
    r0.x = acc[i][0] + bias[0]; r0.y = acc[i][1] + bias[1];
    r0.z = acc[i][2] + bias[2]; r0.w = acc[i][3] + bias[3];
    r1.x = acc[i][4] + bias[4]; r1.y = acc[i][5] + bias[5];
    r1.z = acc[i][6] + bias[6]; r1.w = acc[i][7] + bias[7];
    *(float4*)o = r0;
    *(float4*)(o + 4) = r1;
  }
}

// ============================================================================
// K2: biLSTM recurrence (tc steps per launch), model-parallel, flag sync.
// 256 WGs = dir(2) x batch-group(4 x 16b) x h-slice(32 x 8 rows); Whh slice
// (32 rows = 32 KB) LDS-resident; h exchanged via parity-double-buffered
// global hbuf with agent-scope acquire/release flags. block = 256.
// ============================================================================
__global__ __launch_bounds__(256) void k2_lstm(
    const float* __restrict__ Whh_f, const float* __restrict__ Whh_b,
    const float* __restrict__ xpre_c, float* __restrict__ hout_c,
    float* hbuf, int* flags, float* cstate, int chunk, int tc)
{
  __shared__ float Wt[256][36];   // [k][r], r = g*8+j
  __shared__ float hT[256][20];   // [k][b_local]; aliased as part[] post-GEMM
  float* part = &hT[0][0];        // [(b*32+r)*8 + ks]

  const int tid = threadIdx.x;
  const int wg  = blockIdx.x;
  const int d   = wg >> 7;
  const int bg  = (wg >> 5) & 3;
  const int s   = wg & 31;
  const int b0  = bg * 16;
  const float* Whh = d ? Whh_b : Whh_f;

  {
    int q = tid & 7, r = tid >> 3;
    int g = r >> 3, j = r & 7;
    long R = (long)(g * H_ + s * 8 + j);
#pragma unroll
    for (int i = 0; i < 8; ++i) {
      int k = q * 4 + i * 32;
      float4 w = *(const float4*)(Whh + R * E_ + k);
      Wt[k + 0][r] = w.x; Wt[k + 1][r] = w.y;
      Wt[k + 2][r] = w.z; Wt[k + 3][r] = w.w;
    }
  }
  const int ks = tid >> 5, tl = tid & 31, bt = tl & 3, rt = tl >> 2;
  const int myflag = (d * 4 + bg) * 32 + s;
  const int fbase  = (d * 4 + bg) * 32;

  float c_reg = 0.0f;
  if (chunk > 0 && tid < 128) {
    int bl = tid >> 3, j = tid & 7;
    c_reg = cstate[((size_t)d * B_ + b0 + bl) * H_ + s * 8 + j];
  }
  __syncthreads();

  for (int tt = 1; tt <= tc; ++tt) {
    const int t  = chunk * tc + tt;   // global step 1..512
    const int lt = tt - 1;

    // wait: all 32 producers of this (d,bg) group published h(t-1)
    {
      int* fp = flags + fbase + (tid & 31);
      int lim = 0;
      while (true) {
        int f = __hip_atomic_load(fp, __ATOMIC_ACQUIRE, __HIP_MEMORY_SCOPE_AGENT);
        int bad = (f < t - 1) ? 1 : 0;
        if (__syncthreads_count(bad) == 0) break;
        if (++lim > (1 << 16)) break;   // safety: never hang the harness
      }
    }
    // stage h(t-1) -> hT[k][b_local]
    {
      unsigned long long* hb = (unsigned long long*)(hbuf +
          (size_t)(((t - 1) & 1) * 2 + d) * H_ * B_);
      int j2 = tid & 7, kb = tid >> 3;
#pragma unroll
      for (int i = 0; i < 8; ++i) {
        int k = kb + i * 32;
        unsigned long long v = __hip_atomic_load(
            hb + (size_t)k * 32 + (b0 >> 1) + j2,
            __ATOMIC_RELAXED, __HIP_MEMORY_SCOPE_AGENT);
        float2 f2;
        f2.x = __uint_as_float((unsigned)(v & 0xffffffffull));
        f2.y = __uint_as_float((unsigned)(v >> 32));
        *(float2*)&hT[k][j2 * 2] = f2;
      }
    }
    __syncthreads();

    // GEMM: out[16b][32r] += hT[k][b] * Wt[k][r], k-split 8
    float4 accr[4];
#pragma unroll
    for (int bi = 0; bi < 4; ++bi) accr[bi] = make_float4(0.f, 0.f, 0.f, 0.f);
    {
      const int kb2 = ks * 32;
#pragma unroll 8
      for (int kk = 0; kk < 32; ++kk) {
        int k = kb2 + kk;
        float4 h4 = *(float4*)&hT[k][bt * 4];
        float4 w4 = *(float4*)&Wt[k][rt * 4];
        float ha[4] = {h4.x, h4.y, h4.z, h4.w};
#pragma unroll
        for (int bi = 0; bi < 4; ++bi) {
          accr[bi].x = fmaf(ha[bi], w4.x, accr[bi].x);
          accr[bi].y = fmaf(ha[bi], w4.y, accr[bi].y);
          accr[bi].z = fmaf(ha[bi], w4.z, accr[bi].z);
          accr[bi].w = fmaf(ha[bi], w4.w, accr[bi].w);
        }
      }
    }
    __syncthreads();   // hT reads done; reuse LDS as part[]
#pragma unroll
    for (int bi = 0; bi < 4; ++bi) {
      float vals[4] = {accr[bi].x, accr[bi].y, accr[bi].z, accr[bi].w};
#pragma unroll
      for (int ri = 0; ri < 4; ++ri)
        part[((bt * 4 + bi) * 32 + rt * 4 + ri) * 8 + ks] = vals[ri];
    }
    __syncthreads();

    if (tid < 128) {
      int bl = tid >> 3, j = tid & 7;
      int bglob = b0 + bl;
      float gsum[4];
#pragma unroll
      for (int g = 0; g < 4; ++g) {
        int r = g * 8 + j;
        const float4* pp = (const float4*)&part[(bl * 32 + r) * 8];
        float4 p0 = pp[0], p1 = pp[1];
        float hs = ((p0.x + p0.y) + (p0.z + p0.w)) +
                   ((p1.x + p1.y) + (p1.z + p1.w));
        float xp = xpre_c[((size_t)(d * tc + lt) * B_ + bglob) * G4H_ +
                          g * H_ + s * 8 + j];
        gsum[g] = xp + hs;
      }
      float si = sigmoidf_(gsum[0]);
      float sf = sigmoidf_(gsum[1]);
      float tg = tanhf(gsum[2]);
      float so = sigmoidf_(gsum[3]);
      c_reg = sf * c_reg + si * tg;
      float h = so * tanhf(c_reg);
      hout_c[((size_t)(d * tc + lt) * B_ + bglob) * H_ + s * 8 + j] = h;
      __hip_atomic_store(hbuf + (size_t)((t & 1) * 2 + d) * H_ * B_ +
                             (s * 8 + j) * B_ + bglob,
                         h, __ATOMIC_RELAXED, __HIP_MEMORY_SCOPE_AGENT);
      __threadfence();
    }
    __syncthreads();
    if (tid == 0)
      __hip_atomic_store(flags + myflag, t, __ATOMIC_RELEASE,
                         __HIP_MEMORY_SCOPE_AGENT);
  }

  if (tid < 128) {
    int bl = tid >> 3, j = tid & 7;
    cstate[((size_t)d * B_ + b0 + bl) * H_ + s * 8 + j] = c_reg;
  }
}

// ============================================================================
// K3: per-direction emission contribution.
// emisX[b][tok][tag] = h_d[lt] . Wout[tag][d*256 : d*256+256]
// grid = 64 * (tc/8), block = 256 (192 active in dot).
// ============================================================================
__global__ __launch_bounds__(256) void k3_emis(
    const float* __restrict__ hout_c, const float* __restrict__ Wout,
    float* __restrict__ emisX, int d, int chunk, int tc)
{
  __shared__ float hh[8][264];
  const int tid = threadIdx.x;
  const int nt8 = tc >> 3;
  const int b  = blockIdx.x / nt8;
  const int t8 = blockIdx.x % nt8;
  const int lt0 = t8 * 8;
  {
    int r = tid >> 5, q = tid & 31;
    const float* src = hout_c + ((size_t)(d * tc + lt0 + r) * B_ + b) * H_;
#pragma unroll
    for (int i = 0; i < 2; ++i) {
      int f4i = q + 32 * i;
      *(float4*)&hh[r][f4i * 4] = *(const float4*)(src + f4i * 4);
    }
  }
  __syncthreads();
  if (tid < 192) {
    int r = tid / 24, tag = tid % 24;
    float acc = 0.0f;
    const float* w = Wout + (size_t)tag * 512 + d * 256;
#pragma unroll 4
    for (int k4 = 0; k4 < 64; ++k4) {
      float4 wv = *(const float4*)(w + k4 * 4);
      float4 hv = *(const float4*)&hh[r][k4 * 4];
      acc = fmaf(wv.x, hv.x, acc);
      acc = fmaf(wv.y, hv.y, acc);
      acc = fmaf(wv.z, hv.z, acc);
      acc = fmaf(wv.w, hv.w, acc);
    }
    int lt = lt0 + r;
    int tok = d ? (S_ - 1 - (chunk * tc + lt)) : (chunk * tc + lt);
    emisX[((size_t)b * S_ + tok) * NT_ + tag] = acc;
  }
}

// ============================================================================
// K4: Viterbi forward + backtrack; 1 wave per batch element.
// e = emisF + emisB + bout; fp-assoc matches ref: (score+trans)+e.
// mask dtype sniff: byte[1]==1 => bool(1B) layout, ==0 => int32 layout
// (mask[0][1] is guaranteed True since lengths >= 256).
// ============================================================================
__global__ __launch_bounds__(64) void k4_viterbi(
    const float* __restrict__ emisF, const float* __restrict__ emisB,
    const float* __restrict__ bout, const unsigned char* __restrict__ mb,
    const float* __restrict__ trans, const float* __restrict__ startv,
    const float* __restrict__ endv, int* __restrict__ outp)
{
  __shared__ float tl[24 * 25];
  __shared__ float sc[24];
  __shared__ float fin[24];
  __shared__ unsigned char hist[511 * 24];
  const int b = blockIdx.x;
  const int tid = threadIdx.x;
  const int is_bool = mb[1];

  for (int i = tid; i < 576; i += 64) tl[(i / 24) * 25 + (i % 24)] = trans[i];
  if (tid < 24) {
    size_t e0 = (size_t)b * S_ * NT_ + tid;
    sc[tid] = startv[tid] + (emisF[e0] + emisB[e0] + bout[tid]);
  }
  __syncthreads();

  for (int t = 1; t < S_; ++t) {
    float best = -3.4e38f, scj = 0.f;
    int idx = 0;
    int m;
    {
      int mi = b * S_ + t;
      m = is_bool ? (int)mb[mi] : (int)mb[mi << 2];
    }
    if (tid < 24) {
      size_t ei = ((size_t)b * S_ + t) * NT_ + tid;
      float e = emisF[ei] + emisB[ei] + bout[tid];
      for (int i = 0; i < 24; ++i) {
        float v = (sc[i] + tl[i * 25 + tid]) + e;   // ref assoc order
        if (v > best) { best = v; idx = i; }
      }
      scj = sc[tid];
    }
    __syncthreads();
    if (tid < 24) {
      sc[tid] = m ? best : scj;
      hist[(t - 1) * 24 + tid] = (unsigned char)(m ? idx : tid);
    }
    __syncthreads();
  }
  if (tid < 24) fin[tid] = sc[tid] + endv[tid];
  __syncthreads();
  if (tid == 0) {
    int tag = 0; float best = fin[0];
    for (int i = 1; i < 24; ++i)
      if (fin[i] > best) { best = fin[i]; tag = i; }
    outp[b * S_ + (S_ - 1)] = tag;
    for (int tt = S_ - 2; tt >= 0; --tt) {
      tag = hist[tt * 24 + tag];
      outp[b * S_ + tt] = tag;
    }
  }
}

// ============================================================================
extern "C" void kernel_launch(void* const* d_in, const int* in_sizes, int n_in,
                              void* d_out, int out_size, void* d_ws,
                              size_t ws_size, hipStream_t stream)
{
  const int*   x      = (const int*)d_in[0];
  const unsigned char* maskb = (const unsigned char*)d_in[1];
  const float* emb    = (const float*)d_in[2];
  const float* Wih_f  = (const float*)d_in[3];
  const float* Whh_f  = (const float*)d_in[4];
  const float* bih_f  = (const float*)d_in[5];
  const float* bhh_f  = (const float*)d_in[6];
  const float* Wih_b  = (const float*)d_in[7];
  const float* Whh_b  = (const float*)d_in[8];
  const float* bih_b  = (const float*)d_in[9];
  const float* bhh_b  = (const float*)d_in[10];
  const float* Wout   = (const float*)d_in[11];
  const float* bout   = (const float*)d_in[12];
  const float* trans  = (const float*)d_in[13];
  const float* startv = (const float*)d_in[14];
  const float* endv   = (const float*)d_in[15];

  // pick largest time-chunk that fits ws_size (deterministic: ws_size is fixed)
  int tc = 8;
  {
    const int cand[6] = {512, 256, 128, 64, 32, 16};
    for (int i = 0; i < 6; ++i) {
      size_t needF = HOUT_OFF + (size_t)cand[i] * (2 * B_ * H_ + 2 * B_ * G4H_);
      if (needF * sizeof(float) <= ws_size) { tc = cand[i]; break; }
    }
  }
  const int nc = S_ / tc;

  float* ws     = (float*)d_ws;
  float* hbuf   = ws + HBUF_OFF;
  int*   flags  = (int*)(ws + FLAG_OFF);
  float* cstate = ws + CST_OFF;
  float* emisF  = ws + EMF_OFF;
  float* emisB  = ws + EMB_OFF;
  float* hout_c = ws + HOUT_OFF;
  float* xpre_c = hout_c + (size_t)tc * 2 * B_ * H_;

  // zero hbuf (h(0)=0) + flags; ws is re-poisoned 0xAA before every launch
  hipMemsetAsync(d_ws, 0, (FLAG_OFF - HBUF_OFF + 1024) * sizeof(float), stream);

  for (int c = 0; c < nc; ++c) {
    hipLaunchKernelGGL(k1_xpre, dim3(8 * tc), dim3(256), 0, stream,
                       x, emb, Wih_f, bih_f, bhh_f, Wih_b, bih_b, bhh_b,
                       xpre_c, c, tc);
    hipLaunchKernelGGL(k2_lstm, dim3(256), dim3(256), 0, stream,
                       Whh_f, Whh_b, xpre_c, hout_c, hbuf, flags, cstate, c, tc);
    hipLaunchKernelGGL(k3_emis, dim3(64 * (tc / 8)), dim3(256), 0, stream,
                       hout_c, Wout, emisF, 0, c, tc);
    hipLaunchKernelGGL(k3_emis, dim3(64 * (tc / 8)), dim3(256), 0, stream,
                       hout_c, Wout, emisB, 1, c, tc);
  }
  hipLaunchKernelGGL(k4_viterbi, dim3(64), dim3(64), 0, stream,
                     emisF, emisB, bout, maskb, trans, startv, endv,
                     (int*)d_out);
}

// Round 3
// 4670.308 us; speedup vs baseline: 3.5649x; 3.5649x over previous
//
#include <hip/hip_runtime.h>
#include <math.h>

#define B_   64
#define S_   512
#define E_   256
#define H_   256
#define G4H_ 1024
#define NT_  24

// ---- workspace layout (float-element offsets, all small state at offset 0) ----
static const size_t HBUF_OFF  = 0;        // [2 slot][2 dir][H][B] = 65,536 f
static const size_t FLAG_OFF  = 65536;    // 1024 ints
static const size_t CST_OFF   = 66560;    // [2][B][H] = 32,768 f
static const size_t EMF_OFF   = 99328;    // [B][S][NT]
static const size_t EMB_OFF   = 885760;   // [B][S][NT]
static const size_t HOUT_OFF  = 1672192;  // hout_c then xpre_c (tc-sized)

__device__ __forceinline__ float sigmoidf_(float x) {
  return 1.0f / (1.0f + expf(-x));
}

// ============================================================================
// K1: xpre_c[d][lt][b][:] = emb[x[b][tok]] @ Wih_d^T + (bih_d + bhh_d)
// ============================================================================
__global__ __launch_bounds__(256) void k1_xpre(
    const int* __restrict__ x, const float* __restrict__ emb,
    const float* __restrict__ Wih_f, const float* __restrict__ bih_f,
    const float* __restrict__ bhh_f, const float* __restrict__ Wih_b,
    const float* __restrict__ bih_b, const float* __restrict__ bhh_b,
    float* __restrict__ xpre_c, int chunk, int tc)
{
  __shared__ float As[32][132];   // [k][m]
  __shared__ float Bs[32][132];   // [k][n]
  __shared__ int   xt[128];

  const int tid = threadIdx.x;
  const int wg  = blockIdx.x;
  const int per_dir = 4 * tc;
  const int d   = wg / per_dir;
  const int rem = wg % per_dir;
  const int m0  = (rem >> 3) * 128;
  const int n0  = (rem & 7) * 128;
  const int t0  = chunk * tc;

  const float* Wih = d ? Wih_b : Wih_f;
  const float* bih = d ? bih_b : bih_f;
  const float* bhh = d ? bhh_b : bhh_f;

  if (tid < 128) {
    int m = m0 + tid;
    int lt = m >> 6, b = m & 63;
    int tok = d ? (S_ - 1 - (t0 + lt)) : (t0 + lt);
    xt[tid] = x[b * S_ + tok];
  }
  __syncthreads();

  float acc[8][8];
#pragma unroll
  for (int i = 0; i < 8; ++i)
#pragma unroll
    for (int j = 0; j < 8; ++j) acc[i][j] = 0.0f;

  const int mt8 = tid & 15;
  const int nt8 = tid >> 4;
  const int q = tid & 7, rbase = tid >> 3;

  for (int kc = 0; kc < 8; ++kc) {
    const int k0 = kc * 32;
#pragma unroll
    for (int i = 0; i < 4; ++i) {
      int row = rbase + i * 32;
      float4 a = *(const float4*)(emb + (long)xt[row] * E_ + k0 + q * 4);
      As[q * 4 + 0][row] = a.x; As[q * 4 + 1][row] = a.y;
      As[q * 4 + 2][row] = a.z; As[q * 4 + 3][row] = a.w;
      float4 w = *(const float4*)(Wih + (long)(n0 + row) * E_ + k0 + q * 4);
      Bs[q * 4 + 0][row] = w.x; Bs[q * 4 + 1][row] = w.y;
      Bs[q * 4 + 2][row] = w.z; Bs[q * 4 + 3][row] = w.w;
    }
    __syncthreads();
#pragma unroll
    for (int k = 0; k < 32; ++k) {
      float4 a0 = *(float4*)&As[k][mt8 * 8];
      float4 a1 = *(float4*)&As[k][mt8 * 8 + 4];
      float4 b0 = *(float4*)&Bs[k][nt8 * 8];
      float4 b1 = *(float4*)&Bs[k][nt8 * 8 + 4];
      float am[8] = {a0.x, a0.y, a0.z, a0.w, a1.x, a1.y, a1.z, a1.w};
      float bn[8] = {b0.x, b0.y, b0.z, b0.w, b1.x, b1.y, b1.z, b1.w};
#pragma unroll
      for (int i = 0; i < 8; ++i)
#pragma unroll
        for (int j = 0; j < 8; ++j) acc[i][j] = fmaf(am[i], bn[j], acc[i][j]);
    }
    __syncthreads();
  }

  float bias[8];
  {
    float4 u0 = *(const float4*)(bih + n0 + nt8 * 8);
    float4 u1 = *(const float4*)(bih + n0 + nt8 * 8 + 4);
    float4 v0 = *(const float4*)(bhh + n0 + nt8 * 8);
    float4 v1 = *(const float4*)(bhh + n0 + nt8 * 8 + 4);
    bias[0] = u0.x + v0.x; bias[1] = u0.y + v0.y; bias[2] = u0.z + v0.z;
    bias[3] = u0.w + v0.w; bias[4] = u1.x + v1.x; bias[5] = u1.y + v1.y;
    bias[6] = u1.z + v1.z; bias[7] = u1.w + v1.w;
  }
#pragma unroll
  for (int i = 0; i < 8; ++i) {
    int m = m0 + mt8 * 8 + i;
    int lt = m >> 6, b = m & 63;
    float* o = xpre_c + ((size_t)(d * tc + lt) * B_ + b) * G4H_ + n0 + nt8 * 8;
    float4 r0, r1;
    r0.x = acc[i][0] + bias[0]; r0.y = acc[i][1] + bias[1];
    r0.z = acc[i][2] + bias[2]; r0.w = acc[i][3] + bias[3];
    r1.x = acc[i][4] + bias[4]; r1.y = acc[i][5] + bias[5];
    r1.z = acc[i][6] + bias[6]; r1.w = acc[i][7] + bias[7];
    *(float4*)o = r0;
    *(float4*)(o + 4) = r1;
  }
}

// ============================================================================
// K2: biLSTM recurrence, model-parallel, flag sync via coherence-point
// (agent-scope relaxed) atomics ONLY — no threadfence (no buffer_wbl2), no
// acquire spin (no buffer_inv). Producer orders h-stores before flag with
// s_waitcnt vmcnt(0); consumer polls with one wave, relaxed loads.
// 256 WGs = dir(2) x batch-group(4 x 16b) x h-slice(32 x 8 rows).
// ============================================================================
__global__ __launch_bounds__(256) void k2_lstm(
    const float* __restrict__ Whh_f, const float* __restrict__ Whh_b,
    const float* __restrict__ xpre_c, float* __restrict__ hout_c,
    float* hbuf, int* flags, float* cstate, int chunk, int tc)
{
  __shared__ float Wt[256][36];   // [k][r], r = g*8+j
  __shared__ float hT[256][20];   // [k][b_local]; aliased as part[] post-GEMM
  float* part = &hT[0][0];        // [(b*32+r)*8 + ks]

  const int tid = threadIdx.x;
  const int wg  = blockIdx.x;
  const int d   = wg >> 7;
  const int bg  = (wg >> 5) & 3;
  const int s   = wg & 31;
  const int b0  = bg * 16;
  const float* Whh = d ? Whh_b : Whh_f;

  {
    int q = tid & 7, r = tid >> 3;
    int g = r >> 3, j = r & 7;
    long R = (long)(g * H_ + s * 8 + j);
#pragma unroll
    for (int i = 0; i < 8; ++i) {
      int k = q * 4 + i * 32;
      float4 w = *(const float4*)(Whh + R * E_ + k);
      Wt[k + 0][r] = w.x; Wt[k + 1][r] = w.y;
      Wt[k + 2][r] = w.z; Wt[k + 3][r] = w.w;
    }
  }
  const int ks = tid >> 5, tl = tid & 31, bt = tl & 3, rt = tl >> 2;
  const int myflag = (d * 4 + bg) * 32 + s;
  const int fbase  = (d * 4 + bg) * 32;

  float c_reg = 0.0f;
  if (chunk > 0 && tid < 128) {
    int bl = tid >> 3, j = tid & 7;
    c_reg = cstate[((size_t)d * B_ + b0 + bl) * H_ + s * 8 + j];
  }
  __syncthreads();

  for (int tt = 1; tt <= tc; ++tt) {
    const int t  = chunk * tc + tt;   // global step 1..512
    const int lt = tt - 1;

    // wait: all 32 producers of this (d,bg) group published h(t-1).
    // one wave polls with relaxed (coherence-point) loads; no L2 inv.
    if (tid < 64) {
      const int need = t - 1;
      int lim = 0;
      while (true) {
        int f = need;
        if (tid < 32)
          f = __hip_atomic_load(flags + fbase + tid, __ATOMIC_RELAXED,
                                __HIP_MEMORY_SCOPE_AGENT);
        if (__all(f >= need)) break;
        if (++lim > (1 << 20)) break;   // deadlock safety
      }
    }
    __syncthreads();

    // stage h(t-1) -> hT[k][b_local] (relaxed agent loads: bypass L1/L2)
    {
      unsigned long long* hb = (unsigned long long*)(hbuf +
          (size_t)(((t - 1) & 1) * 2 + d) * H_ * B_);
      int j2 = tid & 7, kb = tid >> 3;
#pragma unroll
      for (int i = 0; i < 8; ++i) {
        int k = kb + i * 32;
        unsigned long long v = __hip_atomic_load(
            hb + (size_t)k * 32 + (b0 >> 1) + j2,
            __ATOMIC_RELAXED, __HIP_MEMORY_SCOPE_AGENT);
        float2 f2;
        f2.x = __uint_as_float((unsigned)(v & 0xffffffffull));
        f2.y = __uint_as_float((unsigned)(v >> 32));
        *(float2*)&hT[k][j2 * 2] = f2;
      }
    }
    __syncthreads();

    // GEMM: out[16b][32r] += hT[k][b] * Wt[k][r], k-split 8
    float4 accr[4];
#pragma unroll
    for (int bi = 0; bi < 4; ++bi) accr[bi] = make_float4(0.f, 0.f, 0.f, 0.f);
    {
      const int kb2 = ks * 32;
#pragma unroll 8
      for (int kk = 0; kk < 32; ++kk) {
        int k = kb2 + kk;
        float4 h4 = *(float4*)&hT[k][bt * 4];
        float4 w4 = *(float4*)&Wt[k][rt * 4];
        float ha[4] = {h4.x, h4.y, h4.z, h4.w};
#pragma unroll
        for (int bi = 0; bi < 4; ++bi) {
          accr[bi].x = fmaf(ha[bi], w4.x, accr[bi].x);
          accr[bi].y = fmaf(ha[bi], w4.y, accr[bi].y);
          accr[bi].z = fmaf(ha[bi], w4.z, accr[bi].z);
          accr[bi].w = fmaf(ha[bi], w4.w, accr[bi].w);
        }
      }
    }
    __syncthreads();   // hT reads done; reuse LDS as part[]
#pragma unroll
    for (int bi = 0; bi < 4; ++bi) {
      float vals[4] = {accr[bi].x, accr[bi].y, accr[bi].z, accr[bi].w};
#pragma unroll
      for (int ri = 0; ri < 4; ++ri)
        part[((bt * 4 + bi) * 32 + rt * 4 + ri) * 8 + ks] = vals[ri];
    }
    __syncthreads();

    if (tid < 128) {
      int bl = tid >> 3, j = tid & 7;
      int bglob = b0 + bl;
      float gsum[4];
#pragma unroll
      for (int g = 0; g < 4; ++g) {
        int r = g * 8 + j;
        const float4* pp = (const float4*)&part[(bl * 32 + r) * 8];
        float4 p0 = pp[0], p1 = pp[1];
        float hs = ((p0.x + p0.y) + (p0.z + p0.w)) +
                   ((p1.x + p1.y) + (p1.z + p1.w));
        float xp = xpre_c[((size_t)(d * tc + lt) * B_ + bglob) * G4H_ +
                          g * H_ + s * 8 + j];
        gsum[g] = xp + hs;
      }
      float si = sigmoidf_(gsum[0]);
      float sf = sigmoidf_(gsum[1]);
      float tg = tanhf(gsum[2]);
      float so = sigmoidf_(gsum[3]);
      c_reg = sf * c_reg + si * tg;
      float h = so * tanhf(c_reg);
      hout_c[((size_t)(d * tc + lt) * B_ + bglob) * H_ + s * 8 + j] = h;
      __hip_atomic_store(hbuf + (size_t)((t & 1) * 2 + d) * H_ * B_ +
                             (s * 8 + j) * B_ + bglob,
                         h, __ATOMIC_RELAXED, __HIP_MEMORY_SCOPE_AGENT);
      // drain this wave's stores to the coherence point (no L2 writeback)
      asm volatile("s_waitcnt vmcnt(0)" ::: "memory");
    }
    __syncthreads();
    if (tid == 0)
      __hip_atomic_store(flags + myflag, t, __ATOMIC_RELAXED,
                         __HIP_MEMORY_SCOPE_AGENT);
  }

  if (tid < 128) {
    int bl = tid >> 3, j = tid & 7;
    cstate[((size_t)d * B_ + b0 + bl) * H_ + s * 8 + j] = c_reg;
  }
}

// ============================================================================
// K3: per-direction emission contribution.
// ============================================================================
__global__ __launch_bounds__(256) void k3_emis(
    const float* __restrict__ hout_c, const float* __restrict__ Wout,
    float* __restrict__ emisX, int d, int chunk, int tc)
{
  __shared__ float hh[8][264];
  const int tid = threadIdx.x;
  const int nt8 = tc >> 3;
  const int b  = blockIdx.x / nt8;
  const int t8 = blockIdx.x % nt8;
  const int lt0 = t8 * 8;
  {
    int r = tid >> 5, q = tid & 31;
    const float* src = hout_c + ((size_t)(d * tc + lt0 + r) * B_ + b) * H_;
#pragma unroll
    for (int i = 0; i < 2; ++i) {
      int f4i = q + 32 * i;
      *(float4*)&hh[r][f4i * 4] = *(const float4*)(src + f4i * 4);
    }
  }
  __syncthreads();
  if (tid < 192) {
    int r = tid / 24, tag = tid % 24;
    float acc = 0.0f;
    const float* w = Wout + (size_t)tag * 512 + d * 256;
#pragma unroll 4
    for (int k4 = 0; k4 < 64; ++k4) {
      float4 wv = *(const float4*)(w + k4 * 4);
      float4 hv = *(const float4*)&hh[r][k4 * 4];
      acc = fmaf(wv.x, hv.x, acc);
      acc = fmaf(wv.y, hv.y, acc);
      acc = fmaf(wv.z, hv.z, acc);
      acc = fmaf(wv.w, hv.w, acc);
    }
    int lt = lt0 + r;
    int tok = d ? (S_ - 1 - (chunk * tc + lt)) : (chunk * tc + lt);
    emisX[((size_t)b * S_ + tok) * NT_ + tag] = acc;
  }
}

// ============================================================================
// K4: Viterbi forward + backtrack; 1 wave per batch element.
// ============================================================================
__global__ __launch_bounds__(64) void k4_viterbi(
    const float* __restrict__ emisF, const float* __restrict__ emisB,
    const float* __restrict__ bout, const unsigned char* __restrict__ mb,
    const float* __restrict__ trans, const float* __restrict__ startv,
    const float* __restrict__ endv, int* __restrict__ outp)
{
  __shared__ float tl[24 * 25];
  __shared__ float sc[24];
  __shared__ float fin[24];
  __shared__ unsigned char hist[511 * 24];
  const int b = blockIdx.x;
  const int tid = threadIdx.x;
  const int is_bool = mb[1];

  for (int i = tid; i < 576; i += 64) tl[(i / 24) * 25 + (i % 24)] = trans[i];
  if (tid < 24) {
    size_t e0 = (size_t)b * S_ * NT_ + tid;
    sc[tid] = startv[tid] + (emisF[e0] + emisB[e0] + bout[tid]);
  }
  __syncthreads();

  for (int t = 1; t < S_; ++t) {
    float best = -3.4e38f, scj = 0.f;
    int idx = 0;
    int m;
    {
      int mi = b * S_ + t;
      m = is_bool ? (int)mb[mi] : (int)mb[mi << 2];
    }
    if (tid < 24) {
      size_t ei = ((size_t)b * S_ + t) * NT_ + tid;
      float e = emisF[ei] + emisB[ei] + bout[tid];
      for (int i = 0; i < 24; ++i) {
        float v = (sc[i] + tl[i * 25 + tid]) + e;   // ref assoc order
        if (v > best) { best = v; idx = i; }
      }
      scj = sc[tid];
    }
    __syncthreads();
    if (tid < 24) {
      sc[tid] = m ? best : scj;
      hist[(t - 1) * 24 + tid] = (unsigned char)(m ? idx : tid);
    }
    __syncthreads();
  }
  if (tid < 24) fin[tid] = sc[tid] + endv[tid];
  __syncthreads();
  if (tid == 0) {
    int tag = 0; float best = fin[0];
    for (int i = 1; i < 24; ++i)
      if (fin[i] > best) { best = fin[i]; tag = i; }
    outp[b * S_ + (S_ - 1)] = tag;
    for (int tt = S_ - 2; tt >= 0; --tt) {
      tag = hist[tt * 24 + tag];
      outp[b * S_ + tt] = tag;
    }
  }
}

// ============================================================================
extern "C" void kernel_launch(void* const* d_in, const int* in_sizes, int n_in,
                              void* d_out, int out_size, void* d_ws,
                              size_t ws_size, hipStream_t stream)
{
  const int*   x      = (const int*)d_in[0];
  const unsigned char* maskb = (const unsigned char*)d_in[1];
  const float* emb    = (const float*)d_in[2];
  const float* Wih_f  = (const float*)d_in[3];
  const float* Whh_f  = (const float*)d_in[4];
  const float* bih_f  = (const float*)d_in[5];
  const float* bhh_f  = (const float*)d_in[6];
  const float* Wih_b  = (const float*)d_in[7];
  const float* Whh_b  = (const float*)d_in[8];
  const float* bih_b  = (const float*)d_in[9];
  const float* bhh_b  = (const float*)d_in[10];
  const float* Wout   = (const float*)d_in[11];
  const float* bout   = (const float*)d_in[12];
  const float* trans  = (const float*)d_in[13];
  const float* startv = (const float*)d_in[14];
  const float* endv   = (const float*)d_in[15];

  int tc = 8;
  {
    const int cand[6] = {512, 256, 128, 64, 32, 16};
    for (int i = 0; i < 6; ++i) {
      size_t needF = HOUT_OFF + (size_t)cand[i] * (2 * B_ * H_ + 2 * B_ * G4H_);
      if (needF * sizeof(float) <= ws_size) { tc = cand[i]; break; }
    }
  }
  const int nc = S_ / tc;

  float* ws     = (float*)d_ws;
  float* hbuf   = ws + HBUF_OFF;
  int*   flags  = (int*)(ws + FLAG_OFF);
  float* cstate = ws + CST_OFF;
  float* emisF  = ws + EMF_OFF;
  float* emisB  = ws + EMB_OFF;
  float* hout_c = ws + HOUT_OFF;
  float* xpre_c = hout_c + (size_t)tc * 2 * B_ * H_;

  hipMemsetAsync(d_ws, 0, (FLAG_OFF - HBUF_OFF + 1024) * sizeof(float), stream);

  for (int c = 0; c < nc; ++c) {
    hipLaunchKernelGGL(k1_xpre, dim3(8 * tc), dim3(256), 0, stream,
                       x, emb, Wih_f, bih_f, bhh_f, Wih_b, bih_b, bhh_b,
                       xpre_c, c, tc);
    hipLaunchKernelGGL(k2_lstm, dim3(256), dim3(256), 0, stream,
                       Whh_f, Whh_b, xpre_c, hout_c, hbuf, flags, cstate, c, tc);
    hipLaunchKernelGGL(k3_emis, dim3(64 * (tc / 8)), dim3(256), 0, stream,
                       hout_c, Wout, emisF, 0, c, tc);
    hipLaunchKernelGGL(k3_emis, dim3(64 * (tc / 8)), dim3(256), 0, stream,
                       hout_c, Wout, emisB, 1, c, tc);
  }
  hipLaunchKernelGGL(k4_viterbi, dim3(64), dim3(64), 0, stream,
                     emisF, emisB, bout, maskb, trans, startv, endv,
                     (int*)d_out);
}

// Round 4
// 3137.025 us; speedup vs baseline: 5.3073x; 1.4888x over previous
//
#include <hip/hip_runtime.h>
#include <math.h>

#define B_   64
#define S_   512
#define E_   256
#define H_   256
#define G4H_ 1024
#define NT_  24

// ---- workspace layout (float-element offsets) ----
// hbuf  : [2 slot][2 dir][256 k][64 b] x {float h, uint tag} = 131072 f (zeroed)
// cstate: [2][B][H] = 32,768 f
// emisF/emisB : [B][S][NT]
// hout_c then xpre_c (tc-sized)
static const size_t HBUF_OFF  = 0;
static const size_t CST_OFF   = 131072;
static const size_t EMF_OFF   = 163840;
static const size_t EMB_OFF   = 950272;
static const size_t HOUT_OFF  = 1736704;

__device__ __forceinline__ float sigmoidf_(float x) {
  return 1.0f / (1.0f + expf(-x));
}

// ============================================================================
// K1: xpre_c[d][lt][b][:] = emb[x[b][tok]] @ Wih_d^T + (bih_d + bhh_d)
// ============================================================================
__global__ __launch_bounds__(256) void k1_xpre(
    const int* __restrict__ x, const float* __restrict__ emb,
    const float* __restrict__ Wih_f, const float* __restrict__ bih_f,
    const float* __restrict__ bhh_f, const float* __restrict__ Wih_b,
    const float* __restrict__ bih_b, const float* __restrict__ bhh_b,
    float* __restrict__ xpre_c, int chunk, int tc)
{
  __shared__ float As[32][132];   // [k][m]
  __shared__ float Bs[32][132];   // [k][n]
  __shared__ int   xt[128];

  const int tid = threadIdx.x;
  const int wg  = blockIdx.x;
  const int per_dir = 4 * tc;
  const int d   = wg / per_dir;
  const int rem = wg % per_dir;
  const int m0  = (rem >> 3) * 128;
  const int n0  = (rem & 7) * 128;
  const int t0  = chunk * tc;

  const float* Wih = d ? Wih_b : Wih_f;
  const float* bih = d ? bih_b : bih_f;
  const float* bhh = d ? bhh_b : bhh_f;

  if (tid < 128) {
    int m = m0 + tid;
    int lt = m >> 6, b = m & 63;
    int tok = d ? (S_ - 1 - (t0 + lt)) : (t0 + lt);
    xt[tid] = x[b * S_ + tok];
  }
  __syncthreads();

  float acc[8][8];
#pragma unroll
  for (int i = 0; i < 8; ++i)
#pragma unroll
    for (int j = 0; j < 8; ++j) acc[i][j] = 0.0f;

  const int mt8 = tid & 15;
  const int nt8 = tid >> 4;
  const int q = tid & 7, rbase = tid >> 3;

  for (int kc = 0; kc < 8; ++kc) {
    const int k0 = kc * 32;
#pragma unroll
    for (int i = 0; i < 4; ++i) {
      int row = rbase + i * 32;
      float4 a = *(const float4*)(emb + (long)xt[row] * E_ + k0 + q * 4);
      As[q * 4 + 0][row] = a.x; As[q * 4 + 1][row] = a.y;
      As[q * 4 + 2][row] = a.z; As[q * 4 + 3][row] = a.w;
      float4 w = *(const float4*)(Wih + (long)(n0 + row) * E_ + k0 + q * 4);
      Bs[q * 4 + 0][row] = w.x; Bs[q * 4 + 1][row] = w.y;
      Bs[q * 4 + 2][row] = w.z; Bs[q * 4 + 3][row] = w.w;
    }
    __syncthreads();
#pragma unroll
    for (int k = 0; k < 32; ++k) {
      float4 a0 = *(float4*)&As[k][mt8 * 8];
      float4 a1 = *(float4*)&As[k][mt8 * 8 + 4];
      float4 b0 = *(float4*)&Bs[k][nt8 * 8];
      float4 b1 = *(float4*)&Bs[k][nt8 * 8 + 4];
      float am[8] = {a0.x, a0.y, a0.z, a0.w, a1.x, a1.y, a1.z, a1.w};
      float bn[8] = {b0.x, b0.y, b0.z, b0.w, b1.x, b1.y, b1.z, b1.w};
#pragma unroll
      for (int i = 0; i < 8; ++i)
#pragma unroll
        for (int j = 0; j < 8; ++j) acc[i][j] = fmaf(am[i], bn[j], acc[i][j]);
    }
    __syncthreads();
  }

  float bias[8];
  {
    float4 u0 = *(const float4*)(bih + n0 + nt8 * 8);
    float4 u1 = *(const float4*)(bih + n0 + nt8 * 8 + 4);
    float4 v0 = *(const float4*)(bhh + n0 + nt8 * 8);
    float4 v1 = *(const float4*)(bhh + n0 + nt8 * 8 + 4);
    bias[0] = u0.x + v0.x; bias[1] = u0.y + v0.y; bias[2] = u0.z + v0.z;
    bias[3] = u0.w + v0.w; bias[4] = u1.x + v1.x; bias[5] = u1.y + v1.y;
    bias[6] = u1.z + v1.z; bias[7] = u1.w + v1.w;
  }
#pragma unroll
  for (int i = 0; i < 8; ++i) {
    int m = m0 + mt8 * 8 + i;
    int lt = m >> 6, b = m & 63;
    float* o = xpre_c + ((size_t)(d * tc + lt) * B_ + b) * G4H_ + n0 + nt8 * 8;
    float4 r0, r1;
    r0.x = acc[i][0] + bias[0]; r0.y = acc[i][1] + bias[1];
    r0.z = acc[i][2] + bias[2]; r0.w = acc[i][3] + bias[3];
    r1.x = acc[i][4] + bias[4]; r1.y = acc[i][5] + bias[5];
    r1.z = acc[i][6] + bias[6]; r1.w = acc[i][7] + bias[7];
    *(float4*)o = r0;
    *(float4*)(o + 4) = r1;
  }
}

// ============================================================================
// K2: biLSTM recurrence with TAG-IN-DATA sync. hbuf entry = 8B {h, step tag},
// stored as one relaxed agent-scope 64-bit atomic: no flags, no vmcnt drain,
// no separate poll round trip. Wave w of each WG owns k-chunk [64w,64w+64):
// it retry-loads exactly the entries its GEMM slice needs, stages them in a
// wave-private hT region, and runs GEMM with no barrier. k-partials reduce
// via shfl_xor(32) + small part[] LDS; only 2 barriers per step.
// 256 WGs = dir(2) x batch-group(4 x 16b) x h-slice(32 x 8 rows).
// ============================================================================
__global__ __launch_bounds__(256) void k2_lstm(
    const float* __restrict__ Whh_f, const float* __restrict__ Whh_b,
    const float* __restrict__ xpre_c, float* __restrict__ hout_c,
    unsigned long long* hbuf, float* cstate, int chunk, int tc)
{
  __shared__ float Wt[256][32];    // [k][r], r = g*8+j   (32,768 B)
  __shared__ float hT[256][20];    // [k][b_local]        (20,480 B)
  __shared__ float part[512 * 4];  // [b*32+r][wave]      ( 8,192 B)

  const int tid = threadIdx.x;
  const int wg  = blockIdx.x;
  const int d   = wg >> 7;
  const int bg  = (wg >> 5) & 3;
  const int s   = wg & 31;
  const int b0  = bg * 16;
  const float* Whh = d ? Whh_b : Whh_f;

  // stage Whh slice -> Wt[k][r]
  {
    int q = tid & 7, r = tid >> 3;
    int g = r >> 3, j = r & 7;
    long R = (long)(g * H_ + s * 8 + j);
#pragma unroll
    for (int i = 0; i < 8; ++i) {
      int k = q * 4 + i * 32;
      float4 w = *(const float4*)(Whh + R * E_ + k);
      Wt[k + 0][r] = w.x; Wt[k + 1][r] = w.y;
      Wt[k + 2][r] = w.z; Wt[k + 3][r] = w.w;
    }
  }
  const int w    = tid >> 6;          // wave 0..3, owns k in [64w, 64w+64)
  const int lane = tid & 63;
  const int bl16 = lane & 15;         // staged batch
  const int kb   = lane >> 4;         // 0..3
  const int ks   = tid >> 5, tl = tid & 31, bt = tl & 3, rt = tl >> 2;
  const int pbl  = tid >> 3, pj = tid & 7;   // pointwise mapping (tid<128)

  float c_reg = 0.0f;
  if (chunk > 0 && tid < 128)
    c_reg = cstate[((size_t)d * B_ + b0 + pbl) * H_ + s * 8 + pj];
  __syncthreads();

  for (int tt = 1; tt <= tc; ++tt) {
    const int t  = chunk * tc + tt;   // global step 1..512
    const int lt = tt - 1;

    // prefetch xpre for this step (independent of h -> off critical path)
    float xp[4];
    if (tid < 128) {
#pragma unroll
      for (int g = 0; g < 4; ++g)
        xp[g] = xpre_c[((size_t)(d * tc + lt) * B_ + b0 + pbl) * G4H_ +
                       g * H_ + s * 8 + pj];
    }

    // stage h(t-1): 16 tagged entries per lane, batched retry on stale tags
    {
      const unsigned expt = (unsigned)(t - 1);
      const unsigned long long* hb =
          hbuf + ((size_t)(((t - 1) & 1) * 2 + d)) * (256 * 64);
      const int kbase = w * 64 + kb * 16;
      const size_t a0 = (size_t)kbase * 64 + b0 + bl16;
      unsigned long long e[16];
#pragma unroll
      for (int i = 0; i < 16; ++i)
        e[i] = __hip_atomic_load(hb + a0 + (size_t)i * 64,
                                 __ATOMIC_RELAXED, __HIP_MEMORY_SCOPE_AGENT);
      int lim = 0;
      while (true) {
        unsigned bad = 0;
#pragma unroll
        for (int i = 0; i < 16; ++i)
          if ((unsigned)(e[i] >> 32) != expt) bad |= (1u << i);
        if (bad == 0) break;
        if (++lim > (1 << 18)) break;   // deadlock safety
#pragma unroll
        for (int i = 0; i < 16; ++i)
          if (bad & (1u << i))
            e[i] = __hip_atomic_load(hb + a0 + (size_t)i * 64,
                                     __ATOMIC_RELAXED,
                                     __HIP_MEMORY_SCOPE_AGENT);
      }
#pragma unroll
      for (int i = 0; i < 16; ++i)
        hT[kbase + i][bl16] = __uint_as_float((unsigned)e[i]);
    }
    // no barrier: this wave's GEMM reads only its own hT rows (lgkmcnt order)

    // GEMM: out[16b][32r] += hT[k][b] * Wt[k][r], half-wave k-split
    float4 accr[4];
#pragma unroll
    for (int bi = 0; bi < 4; ++bi) accr[bi] = make_float4(0.f, 0.f, 0.f, 0.f);
    {
      const int kb2 = ks * 32;
#pragma unroll 8
      for (int kk = 0; kk < 32; ++kk) {
        int k = kb2 + kk;
        float4 h4 = *(float4*)&hT[k][bt * 4];
        float4 w4 = *(float4*)&Wt[k][rt * 4];
        float ha[4] = {h4.x, h4.y, h4.z, h4.w};
#pragma unroll
        for (int bi = 0; bi < 4; ++bi) {
          accr[bi].x = fmaf(ha[bi], w4.x, accr[bi].x);
          accr[bi].y = fmaf(ha[bi], w4.y, accr[bi].y);
          accr[bi].z = fmaf(ha[bi], w4.z, accr[bi].z);
          accr[bi].w = fmaf(ha[bi], w4.w, accr[bi].w);
        }
      }
    }
    // reduce the two half-wave k-chunks in-wave, then publish wave partial
#pragma unroll
    for (int bi = 0; bi < 4; ++bi) {
      accr[bi].x += __shfl_xor(accr[bi].x, 32, 64);
      accr[bi].y += __shfl_xor(accr[bi].y, 32, 64);
      accr[bi].z += __shfl_xor(accr[bi].z, 32, 64);
      accr[bi].w += __shfl_xor(accr[bi].w, 32, 64);
    }
    if (lane < 32) {
#pragma unroll
      for (int bi = 0; bi < 4; ++bi) {
        int eb = (bt * 4 + bi) * 32 + rt * 4;
        part[(eb + 0) * 4 + w] = accr[bi].x;
        part[(eb + 1) * 4 + w] = accr[bi].y;
        part[(eb + 2) * 4 + w] = accr[bi].z;
        part[(eb + 3) * 4 + w] = accr[bi].w;
      }
    }
    __syncthreads();   // B1: all wave partials in part[]

    if (tid < 128) {
      int bglob = b0 + pbl;
      float gsum[4];
#pragma unroll
      for (int g = 0; g < 4; ++g) {
        float4 p = *(float4*)&part[(pbl * 32 + g * 8 + pj) * 4];
        gsum[g] = xp[g] + ((p.x + p.y) + (p.z + p.w));
      }
      float si = sigmoidf_(gsum[0]);
      float sf = sigmoidf_(gsum[1]);
      float tg = tanhf(gsum[2]);
      float so = sigmoidf_(gsum[3]);
      c_reg = sf * c_reg + si * tg;
      float h = so * tanhf(c_reg);
      hout_c[((size_t)(d * tc + lt) * B_ + bglob) * H_ + s * 8 + pj] = h;
      unsigned long long pk =
          (((unsigned long long)(unsigned)t) << 32) |
          (unsigned long long)__float_as_uint(h);
      __hip_atomic_store(hbuf + ((size_t)((t & 1) * 2 + d)) * (256 * 64) +
                             (size_t)(s * 8 + pj) * 64 + bglob,
                         pk, __ATOMIC_RELAXED, __HIP_MEMORY_SCOPE_AGENT);
    }
    __syncthreads();   // B2: part[] reads done before next step overwrites
  }

  if (tid < 128)
    cstate[((size_t)d * B_ + b0 + pbl) * H_ + s * 8 + pj] = c_reg;
}

// ============================================================================
// K3: per-direction emission contribution.
// ============================================================================
__global__ __launch_bounds__(256) void k3_emis(
    const float* __restrict__ hout_c, const float* __restrict__ Wout,
    float* __restrict__ emisX, int d, int chunk, int tc)
{
  __shared__ float hh[8][264];
  const int tid = threadIdx.x;
  const int nt8 = tc >> 3;
  const int b  = blockIdx.x / nt8;
  const int t8 = blockIdx.x % nt8;
  const int lt0 = t8 * 8;
  {
    int r = tid >> 5, q = tid & 31;
    const float* src = hout_c + ((size_t)(d * tc + lt0 + r) * B_ + b) * H_;
#pragma unroll
    for (int i = 0; i < 2; ++i) {
      int f4i = q + 32 * i;
      *(float4*)&hh[r][f4i * 4] = *(const float4*)(src + f4i * 4);
    }
  }
  __syncthreads();
  if (tid < 192) {
    int r = tid / 24, tag = tid % 24;
    float acc = 0.0f;
    const float* w = Wout + (size_t)tag * 512 + d * 256;
#pragma unroll 4
    for (int k4 = 0; k4 < 64; ++k4) {
      float4 wv = *(const float4*)(w + k4 * 4);
      float4 hv = *(const float4*)&hh[r][k4 * 4];
      acc = fmaf(wv.x, hv.x, acc);
      acc = fmaf(wv.y, hv.y, acc);
      acc = fmaf(wv.z, hv.z, acc);
      acc = fmaf(wv.w, hv.w, acc);
    }
    int lt = lt0 + r;
    int tok = d ? (S_ - 1 - (chunk * tc + lt)) : (chunk * tc + lt);
    emisX[((size_t)b * S_ + tok) * NT_ + tag] = acc;
  }
}

// ============================================================================
// K4: Viterbi forward + backtrack; 1 wave per batch element.
// ============================================================================
__global__ __launch_bounds__(64) void k4_viterbi(
    const float* __restrict__ emisF, const float* __restrict__ emisB,
    const float* __restrict__ bout, const unsigned char* __restrict__ mb,
    const float* __restrict__ trans, const float* __restrict__ startv,
    const float* __restrict__ endv, int* __restrict__ outp)
{
  __shared__ float tl[24 * 25];
  __shared__ float sc[24];
  __shared__ float fin[24];
  __shared__ unsigned char hist[511 * 24];
  const int b = blockIdx.x;
  const int tid = threadIdx.x;
  const int is_bool = mb[1];

  for (int i = tid; i < 576; i += 64) tl[(i / 24) * 25 + (i % 24)] = trans[i];
  if (tid < 24) {
    size_t e0 = (size_t)b * S_ * NT_ + tid;
    sc[tid] = startv[tid] + (emisF[e0] + emisB[e0] + bout[tid]);
  }
  __syncthreads();

  for (int t = 1; t < S_; ++t) {
    float best = -3.4e38f, scj = 0.f;
    int idx = 0;
    int m;
    {
      int mi = b * S_ + t;
      m = is_bool ? (int)mb[mi] : (int)mb[mi << 2];
    }
    if (tid < 24) {
      size_t ei = ((size_t)b * S_ + t) * NT_ + tid;
      float e = emisF[ei] + emisB[ei] + bout[tid];
      for (int i = 0; i < 24; ++i) {
        float v = (sc[i] + tl[i * 25 + tid]) + e;   // ref assoc order
        if (v > best) { best = v; idx = i; }
      }
      scj = sc[tid];
    }
    __syncthreads();
    if (tid < 24) {
      sc[tid] = m ? best : scj;
      hist[(t - 1) * 24 + tid] = (unsigned char)(m ? idx : tid);
    }
    __syncthreads();
  }
  if (tid < 24) fin[tid] = sc[tid] + endv[tid];
  __syncthreads();
  if (tid == 0) {
    int tag = 0; float best = fin[0];
    for (int i = 1; i < 24; ++i)
      if (fin[i] > best) { best = fin[i]; tag = i; }
    outp[b * S_ + (S_ - 1)] = tag;
    for (int tt = S_ - 2; tt >= 0; --tt) {
      tag = hist[tt * 24 + tag];
      outp[b * S_ + tt] = tag;
    }
  }
}

// ============================================================================
extern "C" void kernel_launch(void* const* d_in, const int* in_sizes, int n_in,
                              void* d_out, int out_size, void* d_ws,
                              size_t ws_size, hipStream_t stream)
{
  const int*   x      = (const int*)d_in[0];
  const unsigned char* maskb = (const unsigned char*)d_in[1];
  const float* emb    = (const float*)d_in[2];
  const float* Wih_f  = (const float*)d_in[3];
  const float* Whh_f  = (const float*)d_in[4];
  const float* bih_f  = (const float*)d_in[5];
  const float* bhh_f  = (const float*)d_in[6];
  const float* Wih_b  = (const float*)d_in[7];
  const float* Whh_b  = (const float*)d_in[8];
  const float* bih_b  = (const float*)d_in[9];
  const float* bhh_b  = (const float*)d_in[10];
  const float* Wout   = (const float*)d_in[11];
  const float* bout   = (const float*)d_in[12];
  const float* trans  = (const float*)d_in[13];
  const float* startv = (const float*)d_in[14];
  const float* endv   = (const float*)d_in[15];

  int tc = 8;
  {
    const int cand[6] = {512, 256, 128, 64, 32, 16};
    for (int i = 0; i < 6; ++i) {
      size_t needF = HOUT_OFF + (size_t)cand[i] * (2 * B_ * H_ + 2 * B_ * G4H_);
      if (needF * sizeof(float) <= ws_size) { tc = cand[i]; break; }
    }
  }
  const int nc = S_ / tc;

  float* ws     = (float*)d_ws;
  unsigned long long* hbuf = (unsigned long long*)(ws + HBUF_OFF);
  float* cstate = ws + CST_OFF;
  float* emisF  = ws + EMF_OFF;
  float* emisB  = ws + EMB_OFF;
  float* hout_c = ws + HOUT_OFF;
  float* xpre_c = hout_c + (size_t)tc * 2 * B_ * H_;

  // zero hbuf (h(0)=0, tags=0); ws is re-poisoned 0xAA before every launch
  hipMemsetAsync(d_ws, 0, 131072 * sizeof(float), stream);

  for (int c = 0; c < nc; ++c) {
    hipLaunchKernelGGL(k1_xpre, dim3(8 * tc), dim3(256), 0, stream,
                       x, emb, Wih_f, bih_f, bhh_f, Wih_b, bih_b, bhh_b,
                       xpre_c, c, tc);
    hipLaunchKernelGGL(k2_lstm, dim3(256), dim3(256), 0, stream,
                       Whh_f, Whh_b, xpre_c, hout_c, hbuf, cstate, c, tc);
    hipLaunchKernelGGL(k3_emis, dim3(64 * (tc / 8)), dim3(256), 0, stream,
                       hout_c, Wout, emisF, 0, c, tc);
    hipLaunchKernelGGL(k3_emis, dim3(64 * (tc / 8)), dim3(256), 0, stream,
                       hout_c, Wout, emisB, 1, c, tc);
  }
  hipLaunchKernelGGL(k4_viterbi, dim3(64), dim3(64), 0, stream,
                     emisF, emisB, bout, maskb, trans, startv, endv,
                     (int*)d_out);
}

// Round 5
// 2884.994 us; speedup vs baseline: 5.7710x; 1.0874x over previous
//
#include <hip/hip_runtime.h>
#include <math.h>

#define B_   64
#define S_   512
#define E_   256
#define H_   256
#define G4H_ 1024
#define NT_  24

// ---- workspace layout (float-element offsets) ----
// hbuf  : [2 slot][2 dir][256 k][64 b] x {float h, uint tag} = 131072 f (zeroed)
// cstate: [2][B][H]; emisF/emisB: [B][S][NT]; hout_c then xpre_c (tc-sized)
static const size_t HBUF_OFF  = 0;
static const size_t CST_OFF   = 131072;
static const size_t EMF_OFF   = 163840;
static const size_t EMB_OFF   = 950272;
static const size_t HOUT_OFF  = 1736704;

__device__ __forceinline__ float sigmoidf_(float x) {
  return 1.0f / (1.0f + expf(-x));
}

// ============================================================================
// K1: xpre_c[d][lt][b][:] = emb[x[b][tok]] @ Wih_d^T + (bih_d + bhh_d)
// ============================================================================
__global__ __launch_bounds__(256) void k1_xpre(
    const int* __restrict__ x, const float* __restrict__ emb,
    const float* __restrict__ Wih_f, const float* __restrict__ bih_f,
    const float* __restrict__ bhh_f, const float* __restrict__ Wih_b,
    const float* __restrict__ bih_b, const float* __restrict__ bhh_b,
    float* __restrict__ xpre_c, int chunk, int tc)
{
  __shared__ float As[32][132];   // [k][m]
  __shared__ float Bs[32][132];   // [k][n]
  __shared__ int   xt[128];

  const int tid = threadIdx.x;
  const int wg  = blockIdx.x;
  const int per_dir = 4 * tc;
  const int d   = wg / per_dir;
  const int rem = wg % per_dir;
  const int m0  = (rem >> 3) * 128;
  const int n0  = (rem & 7) * 128;
  const int t0  = chunk * tc;

  const float* Wih = d ? Wih_b : Wih_f;
  const float* bih = d ? bih_b : bih_f;
  const float* bhh = d ? bhh_b : bhh_f;

  if (tid < 128) {
    int m = m0 + tid;
    int lt = m >> 6, b = m & 63;
    int tok = d ? (S_ - 1 - (t0 + lt)) : (t0 + lt);
    xt[tid] = x[b * S_ + tok];
  }
  __syncthreads();

  float acc[8][8];
#pragma unroll
  for (int i = 0; i < 8; ++i)
#pragma unroll
    for (int j = 0; j < 8; ++j) acc[i][j] = 0.0f;

  const int mt8 = tid & 15;
  const int nt8 = tid >> 4;
  const int q = tid & 7, rbase = tid >> 3;

  for (int kc = 0; kc < 8; ++kc) {
    const int k0 = kc * 32;
#pragma unroll
    for (int i = 0; i < 4; ++i) {
      int row = rbase + i * 32;
      float4 a = *(const float4*)(emb + (long)xt[row] * E_ + k0 + q * 4);
      As[q * 4 + 0][row] = a.x; As[q * 4 + 1][row] = a.y;
      As[q * 4 + 2][row] = a.z; As[q * 4 + 3][row] = a.w;
      float4 w = *(const float4*)(Wih + (long)(n0 + row) * E_ + k0 + q * 4);
      Bs[q * 4 + 0][row] = w.x; Bs[q * 4 + 1][row] = w.y;
      Bs[q * 4 + 2][row] = w.z; Bs[q * 4 + 3][row] = w.w;
    }
    __syncthreads();
#pragma unroll
    for (int k = 0; k < 32; ++k) {
      float4 a0 = *(float4*)&As[k][mt8 * 8];
      float4 a1 = *(float4*)&As[k][mt8 * 8 + 4];
      float4 b0 = *(float4*)&Bs[k][nt8 * 8];
      float4 b1 = *(float4*)&Bs[k][nt8 * 8 + 4];
      float am[8] = {a0.x, a0.y, a0.z, a0.w, a1.x, a1.y, a1.z, a1.w};
      float bn[8] = {b0.x, b0.y, b0.z, b0.w, b1.x, b1.y, b1.z, b1.w};
#pragma unroll
      for (int i = 0; i < 8; ++i)
#pragma unroll
        for (int j = 0; j < 8; ++j) acc[i][j] = fmaf(am[i], bn[j], acc[i][j]);
    }
    __syncthreads();
  }

  float bias[8];
  {
    float4 u0 = *(const float4*)(bih + n0 + nt8 * 8);
    float4 u1 = *(const float4*)(bih + n0 + nt8 * 8 + 4);
    float4 v0 = *(const float4*)(bhh + n0 + nt8 * 8);
    float4 v1 = *(const float4*)(bhh + n0 + nt8 * 8 + 4);
    bias[0] = u0.x + v0.x; bias[1] = u0.y + v0.y; bias[2] = u0.z + v0.z;
    bias[3] = u0.w + v0.w; bias[4] = u1.x + v1.x; bias[5] = u1.y + v1.y;
    bias[6] = u1.z + v1.z; bias[7] = u1.w + v1.w;
  }
#pragma unroll
  for (int i = 0; i < 8; ++i) {
    int m = m0 + mt8 * 8 + i;
    int lt = m >> 6, b = m & 63;
    float* o = xpre_c + ((size_t)(d * tc + lt) * B_ + b) * G4H_ + n0 + nt8 * 8;
    float4 r0, r1;
    r0.x = acc[i][0] + bias[0]; r0.y = acc[i][1] + bias[1];
    r0.z = acc[i][2] + bias[2]; r0.w = acc[i][3] + bias[3];
    r1.x = acc[i][4] + bias[4]; r1.y = acc[i][5] + bias[5];
    r1.z = acc[i][6] + bias[6]; r1.w = acc[i][7] + bias[7];
    *(float4*)o = r0;
    *(float4*)(o + 4) = r1;
  }
}

// ============================================================================
// K2: biLSTM recurrence, tag-in-data sync. This round:
//  - Whh slice hoisted to 128 VGPRs/thread (GEMM reads only h from LDS)
//  - hTb[b][k] layout: staging via 4 ds_write_b128/lane
//  - part[] double-buffered [2][4][16][36] (conflict-padded) -> single
//    __syncthreads per step (B1); parity buffer makes t vs t+2 reuse safe
//  - hbuf publish issued before hout_c write
// 256 WGs = dir(2) x batch-group(4 x 16b) x h-slice(32 x 8 rows), 1 WG/CU.
// ============================================================================
__global__ __launch_bounds__(256, 1) void k2_lstm(
    const float* __restrict__ Whh_f, const float* __restrict__ Whh_b,
    const float* __restrict__ xpre_c, float* __restrict__ hout_c,
    unsigned long long* hbuf, float* cstate, int chunk, int tc)
{
  __shared__ float hTb[16][260];         // [b_local][k + pad]   (16,640 B)
  __shared__ float part[2][4][16][36];   // [parity][wave][b][r] (18,432 B)

  const int tid = threadIdx.x;
  const int wg  = blockIdx.x;
  const int d   = wg >> 7;
  const int bg  = (wg >> 5) & 3;
  const int s   = wg & 31;
  const int b0  = bg * 16;
  const float* Whh = d ? Whh_b : Whh_f;

  const int w     = tid >> 6;           // wave 0..3
  const int lane  = tid & 63;
  const int bl16  = lane & 15;          // staging batch
  const int kb    = lane >> 4;          // 0..3
  const int kbase = w * 64 + kb * 16;   // staging k range [kbase, kbase+16)
  const int ks    = tid >> 5;           // GEMM k-chunk [32ks, 32ks+32)
  const int tl    = tid & 31, bt = tl & 3, rt = tl >> 2;
  const int pbl   = tid >> 3, pj = tid & 7;   // pointwise mapping (tid<128)

  // hoist this thread's Whh tile into registers: wreg[ri][kk], fixed all steps
  float wreg[4][32];
#pragma unroll
  for (int ri = 0; ri < 4; ++ri) {
    int r = rt * 4 + ri, g = r >> 3, j = r & 7;
    const float* src = Whh + ((size_t)(g * H_ + s * 8 + j)) * H_ + ks * 32;
#pragma unroll
    for (int q = 0; q < 8; ++q) {
      float4 v = *(const float4*)(src + q * 4);
      wreg[ri][q * 4 + 0] = v.x; wreg[ri][q * 4 + 1] = v.y;
      wreg[ri][q * 4 + 2] = v.z; wreg[ri][q * 4 + 3] = v.w;
    }
  }

  float c_reg = 0.0f;
  if (chunk > 0 && tid < 128)
    c_reg = cstate[((size_t)d * B_ + b0 + pbl) * H_ + s * 8 + pj];

  for (int tt = 1; tt <= tc; ++tt) {
    const int t  = chunk * tc + tt;   // global step 1..512
    const int lt = tt - 1;
    const int p  = tt & 1;

    // xpre prefetch (independent of h -> overlaps the poll)
    float xp[4];
    if (tid < 128) {
#pragma unroll
      for (int g = 0; g < 4; ++g)
        xp[g] = xpre_c[((size_t)(d * tc + lt) * B_ + b0 + pbl) * G4H_ +
                       g * H_ + s * 8 + pj];
    }

    // stage h(t-1): 16 tagged entries/lane, batched retry on stale tags
    {
      const unsigned expt = (unsigned)(t - 1);
      const unsigned long long* hb =
          hbuf + ((size_t)(((t - 1) & 1) * 2 + d)) * (256 * 64);
      const size_t a0 = (size_t)kbase * 64 + b0 + bl16;
      unsigned long long e[16];
#pragma unroll
      for (int i = 0; i < 16; ++i)
        e[i] = __hip_atomic_load(hb + a0 + (size_t)i * 64,
                                 __ATOMIC_RELAXED, __HIP_MEMORY_SCOPE_AGENT);
      int lim = 0;
      while (true) {
        unsigned bad = 0;
#pragma unroll
        for (int i = 0; i < 16; ++i)
          if ((unsigned)(e[i] >> 32) != expt) bad |= (1u << i);
        if (bad == 0) break;
        if (++lim > (1 << 18)) break;   // deadlock safety
#pragma unroll
        for (int i = 0; i < 16; ++i)
          if (bad & (1u << i))
            e[i] = __hip_atomic_load(hb + a0 + (size_t)i * 64,
                                     __ATOMIC_RELAXED,
                                     __HIP_MEMORY_SCOPE_AGENT);
      }
      float4 v0, v1, v2, v3;
      v0.x = __uint_as_float((unsigned)e[0]);  v0.y = __uint_as_float((unsigned)e[1]);
      v0.z = __uint_as_float((unsigned)e[2]);  v0.w = __uint_as_float((unsigned)e[3]);
      v1.x = __uint_as_float((unsigned)e[4]);  v1.y = __uint_as_float((unsigned)e[5]);
      v1.z = __uint_as_float((unsigned)e[6]);  v1.w = __uint_as_float((unsigned)e[7]);
      v2.x = __uint_as_float((unsigned)e[8]);  v2.y = __uint_as_float((unsigned)e[9]);
      v2.z = __uint_as_float((unsigned)e[10]); v2.w = __uint_as_float((unsigned)e[11]);
      v3.x = __uint_as_float((unsigned)e[12]); v3.y = __uint_as_float((unsigned)e[13]);
      v3.z = __uint_as_float((unsigned)e[14]); v3.w = __uint_as_float((unsigned)e[15]);
      *(float4*)&hTb[bl16][kbase +  0] = v0;
      *(float4*)&hTb[bl16][kbase +  4] = v1;
      *(float4*)&hTb[bl16][kbase +  8] = v2;
      *(float4*)&hTb[bl16][kbase + 12] = v3;
    }
    // no barrier: wave reads only its own k-columns (same-wave lgkm order)

    // GEMM: acc[bi][ri] += h[b][k] * W[k][r], weights from VGPRs
    float acc[4][4];
#pragma unroll
    for (int bi = 0; bi < 4; ++bi)
#pragma unroll
      for (int ri = 0; ri < 4; ++ri) acc[bi][ri] = 0.0f;
#pragma unroll
    for (int kq = 0; kq < 8; ++kq) {
      const int k0 = ks * 32 + kq * 4;
      float4 h4[4];
#pragma unroll
      for (int bi = 0; bi < 4; ++bi)
        h4[bi] = *(float4*)&hTb[bt * 4 + bi][k0];
#pragma unroll
      for (int kk = 0; kk < 4; ++kk) {
#pragma unroll
        for (int bi = 0; bi < 4; ++bi) {
          const float hv = kk == 0 ? h4[bi].x : kk == 1 ? h4[bi].y
                         : kk == 2 ? h4[bi].z : h4[bi].w;
#pragma unroll
          for (int ri = 0; ri < 4; ++ri)
            acc[bi][ri] = fmaf(hv, wreg[ri][kq * 4 + kk], acc[bi][ri]);
        }
      }
    }
    // reduce the two half-wave k-chunks, publish wave partial (b128)
#pragma unroll
    for (int bi = 0; bi < 4; ++bi)
#pragma unroll
      for (int ri = 0; ri < 4; ++ri)
        acc[bi][ri] += __shfl_xor(acc[bi][ri], 32, 64);
    if (lane < 32) {
#pragma unroll
      for (int bi = 0; bi < 4; ++bi) {
        float4 v = make_float4(acc[bi][0], acc[bi][1], acc[bi][2], acc[bi][3]);
        *(float4*)&part[p][w][bt * 4 + bi][rt * 4] = v;
      }
    }
    __syncthreads();   // B1: wave partials visible to pointwise waves

    if (tid < 128) {
      const int bglob = b0 + pbl;
      float gsum[4];
#pragma unroll
      for (int g = 0; g < 4; ++g) {
        const int r = g * 8 + pj;
        gsum[g] = xp[g] + ((part[p][0][pbl][r] + part[p][1][pbl][r]) +
                           (part[p][2][pbl][r] + part[p][3][pbl][r]));
      }
      float si = sigmoidf_(gsum[0]);
      float sf = sigmoidf_(gsum[1]);
      float tg = tanhf(gsum[2]);
      float so = sigmoidf_(gsum[3]);
      c_reg = sf * c_reg + si * tg;
      float h = so * tanhf(c_reg);
      unsigned long long pk =
          (((unsigned long long)(unsigned)t) << 32) |
          (unsigned long long)__float_as_uint(h);
      __hip_atomic_store(hbuf + ((size_t)((t & 1) * 2 + d)) * (256 * 64) +
                             (size_t)(s * 8 + pj) * 64 + bglob,
                         pk, __ATOMIC_RELAXED, __HIP_MEMORY_SCOPE_AGENT);
      hout_c[((size_t)(d * tc + lt) * B_ + bglob) * H_ + s * 8 + pj] = h;
    }
    // no B2: part is parity-double-buffered; B1 ordering protects reuse
  }

  if (tid < 128)
    cstate[((size_t)d * B_ + b0 + pbl) * H_ + s * 8 + pj] = c_reg;
}

// ============================================================================
// K3: both directions' emission contributions in one launch.
// grid = 2 * 64 * (tc/8), block = 256 (192 active in dot).
// ============================================================================
__global__ __launch_bounds__(256) void k3_emis(
    const float* __restrict__ hout_c, const float* __restrict__ Wout,
    float* __restrict__ emisF, float* __restrict__ emisB, int chunk, int tc)
{
  __shared__ float hh[8][264];
  const int tid = threadIdx.x;
  const int nt8 = tc >> 3;
  const int per_d = 64 * nt8;
  const int d   = blockIdx.x / per_d;
  const int rem = blockIdx.x % per_d;
  const int b   = rem / nt8;
  const int lt0 = (rem % nt8) * 8;
  float* emisX = d ? emisB : emisF;
  {
    int r = tid >> 5, q = tid & 31;
    const float* src = hout_c + ((size_t)(d * tc + lt0 + r) * B_ + b) * H_;
#pragma unroll
    for (int i = 0; i < 2; ++i) {
      int f4i = q + 32 * i;
      *(float4*)&hh[r][f4i * 4] = *(const float4*)(src + f4i * 4);
    }
  }
  __syncthreads();
  if (tid < 192) {
    int r = tid / 24, tag = tid % 24;
    float acc = 0.0f;
    const float* w = Wout + (size_t)tag * 512 + d * 256;
#pragma unroll 4
    for (int k4 = 0; k4 < 64; ++k4) {
      float4 wv = *(const float4*)(w + k4 * 4);
      float4 hv = *(const float4*)&hh[r][k4 * 4];
      acc = fmaf(wv.x, hv.x, acc);
      acc = fmaf(wv.y, hv.y, acc);
      acc = fmaf(wv.z, hv.z, acc);
      acc = fmaf(wv.w, hv.w, acc);
    }
    int lt = lt0 + r;
    int tok = d ? (S_ - 1 - (chunk * tc + lt)) : (chunk * tc + lt);
    emisX[((size_t)b * S_ + tok) * NT_ + tag] = acc;
  }
}

// ============================================================================
// K4: Viterbi forward + backtrack; 1 wave per batch element.
// ============================================================================
__global__ __launch_bounds__(64) void k4_viterbi(
    const float* __restrict__ emisF, const float* __restrict__ emisB,
    const float* __restrict__ bout, const unsigned char* __restrict__ mb,
    const float* __restrict__ trans, const float* __restrict__ startv,
    const float* __restrict__ endv, int* __restrict__ outp)
{
  __shared__ float tl[24 * 25];
  __shared__ float sc[24];
  __shared__ float fin[24];
  __shared__ unsigned char hist[511 * 24];
  const int b = blockIdx.x;
  const int tid = threadIdx.x;
  const int is_bool = mb[1];

  for (int i = tid; i < 576; i += 64) tl[(i / 24) * 25 + (i % 24)] = trans[i];
  if (tid < 24) {
    size_t e0 = (size_t)b * S_ * NT_ + tid;
    sc[tid] = startv[tid] + (emisF[e0] + emisB[e0] + bout[tid]);
  }
  __syncthreads();

  for (int t = 1; t < S_; ++t) {
    float best = -3.4e38f, scj = 0.f;
    int idx = 0;
    int m;
    {
      int mi = b * S_ + t;
      m = is_bool ? (int)mb[mi] : (int)mb[mi << 2];
    }
    if (tid < 24) {
      size_t ei = ((size_t)b * S_ + t) * NT_ + tid;
      float e = emisF[ei] + emisB[ei] + bout[tid];
      for (int i = 0; i < 24; ++i) {
        float v = (sc[i] + tl[i * 25 + tid]) + e;   // ref assoc order
        if (v > best) { best = v; idx = i; }
      }
      scj = sc[tid];
    }
    __syncthreads();
    if (tid < 24) {
      sc[tid] = m ? best : scj;
      hist[(t - 1) * 24 + tid] = (unsigned char)(m ? idx : tid);
    }
    __syncthreads();
  }
  if (tid < 24) fin[tid] = sc[tid] + endv[tid];
  __syncthreads();
  if (tid == 0) {
    int tag = 0; float best = fin[0];
    for (int i = 1; i < 24; ++i)
      if (fin[i] > best) { best = fin[i]; tag = i; }
    outp[b * S_ + (S_ - 1)] = tag;
    for (int tt = S_ - 2; tt >= 0; --tt) {
      tag = hist[tt * 24 + tag];
      outp[b * S_ + tt] = tag;
    }
  }
}

// ============================================================================
extern "C" void kernel_launch(void* const* d_in, const int* in_sizes, int n_in,
                              void* d_out, int out_size, void* d_ws,
                              size_t ws_size, hipStream_t stream)
{
  const int*   x      = (const int*)d_in[0];
  const unsigned char* maskb = (const unsigned char*)d_in[1];
  const float* emb    = (const float*)d_in[2];
  const float* Wih_f  = (const float*)d_in[3];
  const float* Whh_f  = (const float*)d_in[4];
  const float* bih_f  = (const float*)d_in[5];
  const float* bhh_f  = (const float*)d_in[6];
  const float* Wih_b  = (const float*)d_in[7];
  const float* Whh_b  = (const float*)d_in[8];
  const float* bih_b  = (const float*)d_in[9];
  const float* bhh_b  = (const float*)d_in[10];
  const float* Wout   = (const float*)d_in[11];
  const float* bout   = (const float*)d_in[12];
  const float* trans  = (const float*)d_in[13];
  const float* startv = (const float*)d_in[14];
  const float* endv   = (const float*)d_in[15];

  int tc = 8;
  {
    const int cand[6] = {512, 256, 128, 64, 32, 16};
    for (int i = 0; i < 6; ++i) {
      size_t needF = HOUT_OFF + (size_t)cand[i] * (2 * B_ * H_ + 2 * B_ * G4H_);
      if (needF * sizeof(float) <= ws_size) { tc = cand[i]; break; }
    }
  }
  const int nc = S_ / tc;

  float* ws     = (float*)d_ws;
  unsigned long long* hbuf = (unsigned long long*)(ws + HBUF_OFF);
  float* cstate = ws + CST_OFF;
  float* emisF  = ws + EMF_OFF;
  float* emisB  = ws + EMB_OFF;
  float* hout_c = ws + HOUT_OFF;
  float* xpre_c = hout_c + (size_t)tc * 2 * B_ * H_;

  // zero hbuf (h(0)=0, tags=0); ws is re-poisoned 0xAA before every launch
  hipMemsetAsync(d_ws, 0, 131072 * sizeof(float), stream);

  for (int c = 0; c < nc; ++c) {
    hipLaunchKernelGGL(k1_xpre, dim3(8 * tc), dim3(256), 0, stream,
                       x, emb, Wih_f, bih_f, bhh_f, Wih_b, bih_b, bhh_b,
                       xpre_c, c, tc);
    hipLaunchKernelGGL(k2_lstm, dim3(256), dim3(256), 0, stream,
                       Whh_f, Whh_b, xpre_c, hout_c, hbuf, cstate, c, tc);
    hipLaunchKernelGGL(k3_emis, dim3(2 * 64 * (tc / 8)), dim3(256), 0, stream,
                       hout_c, Wout, emisF, emisB, c, tc);
  }
  hipLaunchKernelGGL(k4_viterbi, dim3(64), dim3(64), 0, stream,
                     emisF, emisB, bout, maskb, trans, startv, endv,
                     (int*)d_out);
}